// Round 3
// baseline (1020.629 us; speedup 1.0000x reference)
//
#include <hip/hip_runtime.h>
#include <math.h>

#define NN 50000
#define GG 8
#define HEADS 4
#define CH 32
#define HID 128
#define NLAYER 3
#define POOL_S 64
#define CSR_CAP 1600000

// ---------------- static device scratch ----------------
__device__ float g_h[(size_t)NN * HID];     // layer activations (edge-pass output)
__device__ float g_h2[(size_t)NN * HID];    // per-layer GEMM output
__device__ float g_as[(size_t)NN * HEADS];
__device__ float g_ad[(size_t)NN * HEADS];
__device__ int g_counts[NN];
__device__ int g_cursor[NN];
__device__ int g_off[NN + 1];
__device__ int g_csr[CSR_CAP];
__device__ int g_starts[GG + 1];
__device__ double g_psum[(size_t)GG * POOL_S * HID];
__device__ float g_pmax[(size_t)GG * POOL_S * HID];
__device__ float g_pvec[GG * 256];
__device__ float g_m1[GG * 256];
__device__ float g_m2[GG * 128];

__device__ __forceinline__ float lrelu(float v) { return v > 0.f ? v : 0.2f * v; }

// ---------------- init ----------------
__global__ void zero_kernel() {
    int i = blockIdx.x * blockDim.x + threadIdx.x;
    if (i < NN) { g_counts[i] = 0; g_cursor[i] = 0; }
}

// ---------------- CSR build (indices are int32 per harness contract) ----------------
__global__ void hist_kernel(const int* __restrict__ dst, int e) {
    int idx = blockIdx.x * blockDim.x + threadIdx.x;
    int stride = gridDim.x * blockDim.x;
    for (int j = idx; j < e; j += stride) atomicAdd(&g_counts[dst[j]], 1);
}

__global__ __launch_bounds__(1024) void scan_kernel() {
    __shared__ int lsum[1024];
    int t = threadIdx.x;
    int chunk = (NN + 1023) / 1024;
    int s0 = t * chunk, s1 = s0 + chunk;
    if (s0 > NN) s0 = NN;
    if (s1 > NN) s1 = NN;
    int s = 0;
    for (int i = s0; i < s1; i++) s += g_counts[i];
    lsum[t] = s;
    __syncthreads();
    for (int d = 1; d < 1024; d <<= 1) {
        int v = 0;
        if (t >= d) v = lsum[t - d];
        __syncthreads();
        lsum[t] += v;
        __syncthreads();
    }
    int run = (t == 0) ? 0 : lsum[t - 1];
    for (int i = s0; i < s1; i++) { g_off[i] = run; run += g_counts[i]; }
    if (t == 1023) g_off[NN] = lsum[1023];
}

__global__ void scatter_kernel(const int* __restrict__ srcv,
                               const int* __restrict__ dstv, int e) {
    int idx = blockIdx.x * blockDim.x + threadIdx.x;
    int stride = gridDim.x * blockDim.x;
    for (int j = idx; j < e; j += stride) {
        int d = dstv[j];
        int pos = atomicAdd(&g_cursor[d], 1);
        int p = g_off[d] + pos;
        if (p < CSR_CAP) g_csr[p] = srcv[j];
    }
}

// ---------------- GEMM (fp32, 128 rows/block, 8x8 reg tile, K-chunked LDS) ----------------
template <int K, bool ATT, bool RELU, bool SRC_PARAM>
__global__ __launch_bounds__(256) void gemm_kernel(
    const float* __restrict__ Xp, const float* __restrict__ W, const float* __restrict__ bias,
    const float* __restrict__ att_s, const float* __restrict__ att_d, int n) {
    constexpr int KT = 32;
    constexpr int XS = 132;  // padded stride along rows
    __shared__ float Ws[KT * 128];
    __shared__ float Xs[KT * XS];
    const float* X = SRC_PARAM ? Xp : g_h;
    float* Y = ATT ? g_h2 : g_h;
    int tid = threadIdx.x;
    int base = blockIdx.x * 128;
    int rows = n - base;
    if (rows > 128) rows = 128;
    int cg = tid & 15, rg = tid >> 4;
    int c0 = cg * 8, r0 = rg * 8;
    float acc[8][8];
#pragma unroll
    for (int i = 0; i < 8; i++)
#pragma unroll
        for (int j = 0; j < 8; j++) acc[i][j] = 0.f;

    for (int kb = 0; kb < K; kb += KT) {
        for (int i = tid; i < KT * 128; i += 256) Ws[i] = W[kb * 128 + i];
        for (int i = tid; i < KT * 128; i += 256) {
            int r = i >> 5, k = i & 31;
            float v = 0.f;
            if (r < rows) v = X[(size_t)(base + r) * K + kb + k];
            Xs[k * XS + r] = v;
        }
        __syncthreads();
#pragma unroll 8
        for (int k = 0; k < KT; k++) {
            const float4 xa = *(const float4*)&Xs[k * XS + r0];
            const float4 xb = *(const float4*)&Xs[k * XS + r0 + 4];
            const float4 wa = *(const float4*)&Ws[k * 128 + c0];
            const float4 wb = *(const float4*)&Ws[k * 128 + c0 + 4];
            const float xr[8] = {xa.x, xa.y, xa.z, xa.w, xb.x, xb.y, xb.z, xb.w};
            const float wr[8] = {wa.x, wa.y, wa.z, wa.w, wb.x, wb.y, wb.z, wb.w};
#pragma unroll
            for (int ii = 0; ii < 8; ii++)
#pragma unroll
                for (int jj = 0; jj < 8; jj++) acc[ii][jj] += xr[ii] * wr[jj];
        }
        __syncthreads();
    }

    float bv[8];
#pragma unroll
    for (int j = 0; j < 8; j++) bv[j] = bias ? bias[c0 + j] : 0.f;
#pragma unroll
    for (int ii = 0; ii < 8; ii++) {
        int r = r0 + ii;
        if (r < rows) {
            float o[8];
#pragma unroll
            for (int jj = 0; jj < 8; jj++) {
                o[jj] = acc[ii][jj] + bv[jj];
                if (RELU) o[jj] = fmaxf(o[jj], 0.f);
            }
            float4 oa = {o[0], o[1], o[2], o[3]};
            float4 ob = {o[4], o[5], o[6], o[7]};
            *(float4*)&Y[(size_t)(base + r) * 128 + c0] = oa;
            *(float4*)&Y[(size_t)(base + r) * 128 + c0 + 4] = ob;
        }
    }

    if constexpr (ATT) {
        float avs[8], avd[8];
#pragma unroll
        for (int j = 0; j < 8; j++) { avs[j] = att_s[c0 + j]; avd[j] = att_d[c0 + j]; }
#pragma unroll
        for (int ii = 0; ii < 8; ii++) {
            float ps = 0.f, pd = 0.f;
#pragma unroll
            for (int jj = 0; jj < 8; jj++) { ps += acc[ii][jj] * avs[jj]; pd += acc[ii][jj] * avd[jj]; }
            ps += __shfl_xor(ps, 1); ps += __shfl_xor(ps, 2);
            pd += __shfl_xor(pd, 1); pd += __shfl_xor(pd, 2);
            int r = r0 + ii;
            if ((cg & 3) == 0 && r < rows) {
                g_as[(size_t)(base + r) * 4 + (cg >> 2)] = ps;
                g_ad[(size_t)(base + r) * 4 + (cg >> 2)] = pd;
            }
        }
    }
}

// ---------------- GAT edge pass: one wave per dst node ----------------
__global__ __launch_bounds__(256) void gat_edge_kernel(const float* __restrict__ bconv) {
    int gid = blockIdx.x * blockDim.x + threadIdx.x;
    int i = gid >> 6;
    int lane = threadIdx.x & 63;
    if (i >= NN) return;
    int b0 = g_off[i], b1 = g_off[i + 1];
    int deg = b1 - b0;
    float4 ad = *(const float4*)&g_ad[(size_t)i * 4];
    float4 asi = *(const float4*)&g_as[(size_t)i * 4];
    float e0 = lrelu(asi.x + ad.x), e1 = lrelu(asi.y + ad.y);
    float e2 = lrelu(asi.z + ad.z), e3 = lrelu(asi.w + ad.w);
    float m0 = e0, m1 = e1, m2 = e2, m3 = e3;
    for (int j = lane; j < deg; j += 64) {
        int s = g_csr[b0 + j];
        float4 a = *(const float4*)&g_as[(size_t)s * 4];
        m0 = fmaxf(m0, lrelu(a.x + ad.x));
        m1 = fmaxf(m1, lrelu(a.y + ad.y));
        m2 = fmaxf(m2, lrelu(a.z + ad.z));
        m3 = fmaxf(m3, lrelu(a.w + ad.w));
    }
#pragma unroll
    for (int d = 1; d < 64; d <<= 1) {
        m0 = fmaxf(m0, __shfl_xor(m0, d));
        m1 = fmaxf(m1, __shfl_xor(m1, d));
        m2 = fmaxf(m2, __shfl_xor(m2, d));
        m3 = fmaxf(m3, __shfl_xor(m3, d));
    }
    int hl = lane >> 4;  // head owning channels 2*lane, 2*lane+1
    float mh = hl == 0 ? m0 : hl == 1 ? m1 : hl == 2 ? m2 : m3;
    float adh = hl == 0 ? ad.x : hl == 1 ? ad.y : hl == 2 ? ad.z : ad.w;
    float eh = hl == 0 ? e0 : hl == 1 ? e1 : hl == 2 ? e2 : e3;
    int c0 = lane * 2;
    float w = expf(eh - mh);  // self loop
    float z = w;
    float2 hv = *(const float2*)&g_h2[(size_t)i * 128 + c0];
    float a0 = w * hv.x, a1 = w * hv.y;
    int s_next = deg > 0 ? g_csr[b0] : 0;
    for (int j = 0; j < deg; j++) {
        int s = s_next;
        if (j + 1 < deg) s_next = g_csr[b0 + j + 1];
        float av = g_as[(size_t)s * 4 + hl];
        float e = lrelu(av + adh);
        float wj = expf(e - mh);
        z += wj;
        float2 hs = *(const float2*)&g_h2[(size_t)s * 128 + c0];
        a0 += wj * hs.x;
        a1 += wj * hs.y;
    }
    float inv = 1.f / (z + 1e-16f);
    float2 o;
    o.x = fmaxf(a0 * inv + bconv[c0], 0.f);
    o.y = fmaxf(a1 * inv + bconv[c0 + 1], 0.f);
    *(float2*)&g_h[(size_t)i * 128 + c0] = o;
}

// ---------------- pooling ----------------
__global__ void bounds_kernel(const int* __restrict__ batch) {
    int t = threadIdx.x;
    if (t > GG) return;
    int lo = 0, hi = NN;
    while (lo < hi) {
        int mid = (lo + hi) >> 1;
        if (batch[mid] < t) lo = mid + 1; else hi = mid;
    }
    g_starts[t] = lo;
}

__global__ void pool1_kernel() {
    int g = blockIdx.x / POOL_S, s = blockIdx.x % POOL_S;
    int n0 = g_starts[g], n1 = g_starts[g + 1];
    long long cnt = n1 - n0;
    int a = n0 + (int)(cnt * s / POOL_S);
    int b = n0 + (int)(cnt * (s + 1) / POOL_S);
    int c = threadIdx.x;
    double sum = 0.0;
    float mx = -INFINITY;
    for (int nn = a; nn < b; nn++) {
        float v = g_h[(size_t)nn * 128 + c];
        sum += v;
        mx = fmaxf(mx, v);
    }
    g_psum[(size_t)blockIdx.x * 128 + c] = sum;
    g_pmax[(size_t)blockIdx.x * 128 + c] = mx;
}

__global__ void pool2_kernel() {
    int g = blockIdx.x, c = threadIdx.x;
    double sum = 0.0;
    float mx = -INFINITY;
    for (int s = 0; s < POOL_S; s++) {
        sum += g_psum[(size_t)(g * POOL_S + s) * 128 + c];
        mx = fmaxf(mx, g_pmax[(size_t)(g * POOL_S + s) * 128 + c]);
    }
    int cnt = g_starts[g + 1] - g_starts[g];
    double dcnt = cnt > 0 ? (double)cnt : 1.0;
    float mean = (float)(sum / dcnt);
    if (cnt <= 0) mx = 0.f;
    g_pvec[g * 256 + c] = mean;
    g_pvec[g * 256 + 128 + c] = mx;
}

// ---------------- MLP ----------------
__global__ void mlp1_kernel(const float* __restrict__ W, const float* __restrict__ b) {
    int g = blockIdx.x, j = threadIdx.x;
    float acc = b[j];
    for (int k = 0; k < 256; k++) acc += g_pvec[g * 256 + k] * W[k * 256 + j];
    g_m1[g * 256 + j] = fmaxf(acc, 0.f);
}

__global__ void mlp2_kernel(const float* __restrict__ W, const float* __restrict__ b) {
    int g = blockIdx.x, j = threadIdx.x;
    float acc = b[j];
    for (int k = 0; k < 256; k++) acc += g_m1[g * 256 + k] * W[k * 128 + j];
    g_m2[g * 128 + j] = fmaxf(acc, 0.f);
}

__global__ void mlp3_kernel(const float* __restrict__ W3, const float* __restrict__ b3,
                            float* __restrict__ outv) {
    int g = threadIdx.x >> 6;
    int lane = threadIdx.x & 63;
    float acc = g_m2[g * 128 + lane] * W3[lane] + g_m2[g * 128 + 64 + lane] * W3[64 + lane];
#pragma unroll
    for (int d = 32; d >= 1; d >>= 1) acc += __shfl_down(acc, d);
    if (lane == 0) outv[g] = acc + b3[0];
}

extern "C" void kernel_launch(void* const* d_in, const int* in_sizes, int n_in,
                              void* d_out, int out_size, void* d_ws, size_t ws_size,
                              hipStream_t stream) {
    const float* x = (const float*)d_in[0];
    const int* eidx = (const int*)d_in[1];     // int64 in reference -> int32 from harness
    const int* batch = (const int*)d_in[2];    // int64 in reference -> int32 from harness
    const float* Wp = (const float*)d_in[3];
    const float* bp = (const float*)d_in[4];
    const float* Wl = (const float*)d_in[5];
    const float* att_src = (const float*)d_in[6];
    const float* att_dst = (const float*)d_in[7];
    const float* bconv = (const float*)d_in[8];
    const float* W1 = (const float*)d_in[9];
    const float* b1 = (const float*)d_in[10];
    const float* W2 = (const float*)d_in[11];
    const float* b2 = (const float*)d_in[12];
    const float* W3 = (const float*)d_in[13];
    const float* b3 = (const float*)d_in[14];
    float* out = (float*)d_out;
    int E = in_sizes[1] / 2;
    if (E > CSR_CAP) E = CSR_CAP;

    zero_kernel<<<(NN + 255) / 256, 256, 0, stream>>>();
    hist_kernel<<<1024, 256, 0, stream>>>(eidx + E, E);
    scan_kernel<<<1, 1024, 0, stream>>>();
    scatter_kernel<<<1024, 256, 0, stream>>>(eidx, eidx + E, E);

    gemm_kernel<64, false, true, true><<<(NN + 127) / 128, 256, 0, stream>>>(
        x, Wp, bp, nullptr, nullptr, NN);

    for (int l = 0; l < NLAYER; l++) {
        gemm_kernel<128, true, false, false><<<(NN + 127) / 128, 256, 0, stream>>>(
            nullptr, Wl + (size_t)l * HID * HID, nullptr,
            att_src + (size_t)l * HEADS * CH, att_dst + (size_t)l * HEADS * CH, NN);
        gat_edge_kernel<<<(NN * 64 + 255) / 256, 256, 0, stream>>>(bconv + (size_t)l * HID);
    }

    bounds_kernel<<<1, 64, 0, stream>>>(batch);
    pool1_kernel<<<GG * POOL_S, 128, 0, stream>>>();
    pool2_kernel<<<GG, 128, 0, stream>>>();
    mlp1_kernel<<<GG, 256, 0, stream>>>(W1, b1);
    mlp2_kernel<<<GG, 128, 0, stream>>>(W2, b2);
    mlp3_kernel<<<1, 512, 0, stream>>>(W3, b3, out);
}